// Round 4
// baseline (199.476 us; speedup 1.0000x reference)
//
#include <hip/hip_runtime.h>
#include <hip/hip_bf16.h>
#include <math.h>

typedef unsigned short ushort;
typedef __attribute__((ext_vector_type(8))) short bf16x8;
typedef __attribute__((ext_vector_type(4))) float f32x4;
typedef __attribute__((ext_vector_type(8))) ushort ushort8;
typedef __attribute__((ext_vector_type(4))) ushort ushort4_t;

__device__ inline ushort f2bf(float f) {
  __hip_bfloat16 h = __float2bfloat16(f);
  return *reinterpret_cast<ushort*>(&h);
}
__device__ inline float bf2f(ushort u) {
  unsigned int v = ((unsigned int)u) << 16;
  return __builtin_bit_cast(float, v);
}

typedef __attribute__((address_space(3))) unsigned int lds_u32;
typedef __attribute__((address_space(1))) const unsigned int glb_u32;
__device__ __forceinline__ void gl2lds16(const ushort* g, ushort* l) {
  __builtin_amdgcn_global_load_lds((glb_u32*)g, (lds_u32*)l, 16, 0, 0);
}

#define S_BARRIER asm volatile("s_barrier" ::: "memory")
#define WAITV0 asm volatile("s_waitcnt vmcnt(0)" ::: "memory")
#define WAITV2 asm volatile("s_waitcnt vmcnt(2)" ::: "memory")
#define WAITV4 asm volatile("s_waitcnt vmcnt(4)" ::: "memory")

// ============================ pack_all =====================================
// blocks [0,264): x NCHW f32 -> padded NHWC bf16 [b][66][66][64] (borders 0)
// blocks [264,328): w1 OIHW -> [tap][256][64]
// blocks [328,1352): w2 OIHW -> [tap][1024][256]
// blocks [1352,2392): zero borders of h1n_pad [b][66][66][256]
__global__ __launch_bounds__(256) void pack_all(
    const float* __restrict__ x, const float* __restrict__ w1,
    const float* __restrict__ w2, ushort* __restrict__ xn_pad,
    ushort* __restrict__ w1p, ushort* __restrict__ w2p,
    ushort* __restrict__ h1n_pad) {
  int blk = blockIdx.x;
  int tid = threadIdx.x;
  __shared__ float ld[64][65];
  if (blk < 264) {
    int b = blk / 66, yp = blk % 66;
    ushort* dst = xn_pad + (size_t)(b * 66 + yp) * 66 * 64;
    if (yp == 0 || yp == 65) {
      for (int i = tid; i < 66 * 64; i += 256) dst[i] = 0;
      return;
    }
    int y = yp - 1;
    int xx = tid & 63;
#pragma unroll
    for (int i = 0; i < 16; ++i) {
      int c = i * 4 + (tid >> 6);
      ld[c][xx] = x[((b * 64 + c) * 64 + y) * 64 + xx];
    }
    __syncthreads();
    for (int i = tid; i < 2 * 64; i += 256) {
      int side = i >> 6, c = i & 63;
      dst[(side ? 65 : 0) * 64 + c] = 0;
    }
    for (int u = tid; u < 64 * 8; u += 256) {
      int xp = u >> 3, cg = u & 7;
      ushort8 v;
#pragma unroll
      for (int j = 0; j < 8; ++j) v[j] = f2bf(ld[cg * 8 + j][xp]);
      *reinterpret_cast<ushort8*>(&dst[(xp + 1) * 64 + cg * 8]) = v;
    }
  } else if (blk < 328) {
    int idx = (blk - 264) * 256 + tid;  // OC=256, CIN=64
    float v[9];
#pragma unroll
    for (int t = 0; t < 9; ++t) v[t] = w1[idx * 9 + t];
    int oc = idx >> 6, c = idx & 63;
#pragma unroll
    for (int t = 0; t < 9; ++t) w1p[(t * 256 + oc) * 64 + c] = f2bf(v[t]);
  } else if (blk < 1352) {
    int idx = (blk - 328) * 256 + tid;  // OC=1024, CIN=256
    float v[9];
#pragma unroll
    for (int t = 0; t < 9; ++t) v[t] = w2[(size_t)idx * 9 + t];
    int oc = idx >> 8, c = idx & 255;
#pragma unroll
    for (int t = 0; t < 9; ++t)
      w2p[((size_t)t * 1024 + oc) * 256 + c] = f2bf(v[t]);
  } else {
    int k = blk - 1352;  // 0..1039
    int b = k / 260, p = k % 260;
    int yp, xp;
    if (p < 66) { yp = 0; xp = p; }
    else if (p < 132) { yp = 65; xp = p - 66; }
    else if (p < 196) { yp = p - 132 + 1; xp = 0; }
    else { yp = p - 196 + 1; xp = 65; }
    h1n_pad[((size_t)(b * 66 + yp) * 66 + xp) * 256 + tid] = 0;
  }
}

// ================= pipelined implicit-GEMM conv (3x3, pad 1) ================
// in_pad: [b][66][66][CIN] bf16, zero borders. wpack: [9][NOC][CIN].
// WMF=4: BM=256, BN=128, waves 4Mx2N (wave tile 64x64)   [conv1]
// WMF=8: BM=256, BN=256, waves 2Mx4N (wave tile 128x64)  [conv2]
// K-step = (cb, tap) = 64. A staged per cb (swizzled src), B triple-buffered
// via global_load_lds, prefetch distance 2, counted vmcnt. setprio on MFMA.
template<int C1B, int NOC, int WMF, bool POUT>
__global__ __launch_bounds__(512) void conv_gemm2(
    const ushort* __restrict__ in_pad, const ushort* __restrict__ wpack,
    const float* __restrict__ bias, ushort* __restrict__ outp) {
  constexpr int CIN = C1B * 64;
  constexpr int NSTEP = C1B * 9;
  constexpr int NWN = (WMF == 8) ? 4 : 2;
  constexpr int BN = NWN * 64;
  constexpr int SB = BN / 64;        // stageB gl2lds16 per thread
  constexpr int BUFU = BN * 64;      // ushorts per B buffer
  extern __shared__ ushort lds[];
  ushort* Araw = lds;                // 3584 chunks x 16B = 57344 B
  ushort* Bb = lds + 28672;          // 3 x BUFU ushorts
  int tid = threadIdx.x;
  int wid = tid >> 6, lane = tid & 63;
  int lrow = lane & 15, lk = lane >> 4;
  int wm = wid / NWN, wn = wid % NWN;
  int P0 = blockIdx.x * 256;
  int b = P0 >> 12;
  int y0 = (P0 & 4095) >> 6;
  int ocB = blockIdx.y * BN;
  f32x4 acc[WMF][4] = {};

  auto stageA = [&](int cb) {
    const ushort* asrc = in_pad + (size_t)(b * 66 + y0) * 66 * CIN + cb * 64;
#pragma unroll
    for (int it = 0; it < 7; ++it) {
      int basech = it * 512 + wid * 64;
      int ch = basech + lane;
      int ry = ch / 528, rem = ch % 528;
      int xs = rem >> 3, cg = rem & 7;
      int cgp = cg ^ (xs & 7);
      gl2lds16(asrc + (size_t)(ry * 66 + xs) * CIN + cgp * 8,
               Araw + basech * 8);
    }
  };
  auto stageB = [&](int sstep, int q) {
    int st = sstep % 9;
    int scb = sstep / 9;
    const ushort* wsrc = wpack + ((size_t)st * NOC + ocB) * CIN + scb * 64;
    ushort* dbase = Bb + q * BUFU;
#pragma unroll
    for (int it = 0; it < SB; ++it) {
      int basech = it * 512 + wid * 64;
      int ch = basech + lane;
      int oc = ch >> 3, cg = ch & 7;
      int cgp = cg ^ (oc & 7);
      gl2lds16(wsrc + (size_t)oc * CIN + cgp * 8, dbase + basech * 8);
    }
  };

  // prologue
  stageA(0);
  stageB(0, 0);
  stageB(1, 1);
  if constexpr (SB == 2) { WAITV2; } else { WAITV4; }
  S_BARRIER;

#pragma unroll 1
  for (int cb = 0; cb < C1B; ++cb) {
#pragma unroll 1
    for (int t = 0; t < 9; ++t) {
      int step = cb * 9 + t;
      int cur = step % 3;
      if (step + 2 < NSTEP) stageB(step + 2, (step + 2) % 3);
      int ky = t / 3, kx = t - ky * 3;
      const ushort* bcur = Bb + cur * BUFU;
#pragma unroll
      for (int ks = 0; ks < 2; ++ks) {
        bf16x8 af[WMF], bfv[4];
#pragma unroll
        for (int mf = 0; mf < WMF; ++mf) {
          int mwave = mf * 16 + lrow;
          int xs = (mwave & 63) + kx;
          int row = (wm * (WMF / 4) + (mwave >> 6) + ky) * 66 + xs;
          int kboff = (ks * 64 + lk * 16) ^ ((xs & 7) << 4);
          af[mf] =
              *reinterpret_cast<const bf16x8*>(Araw + row * 64 + (kboff >> 1));
        }
#pragma unroll
        for (int nf = 0; nf < 4; ++nf) {
          int oc_l = wn * 64 + nf * 16 + lrow;
          int kboff = (ks * 64 + lk * 16) ^ ((oc_l & 7) << 4);
          bfv[nf] =
              *reinterpret_cast<const bf16x8*>(bcur + oc_l * 64 + (kboff >> 1));
        }
        __builtin_amdgcn_s_setprio(1);
#pragma unroll
        for (int mf = 0; mf < WMF; ++mf)
#pragma unroll
          for (int nf = 0; nf < 4; ++nf)
            acc[mf][nf] = __builtin_amdgcn_mfma_f32_16x16x32_bf16(
                af[mf], bfv[nf], acc[mf][nf], 0, 0, 0);
        __builtin_amdgcn_s_setprio(0);
      }
      if (t == 8 && cb + 1 < C1B) {
        S_BARRIER;          // all waves done reading Araw
        stageA(cb + 1);
        WAITV0;
        S_BARRIER;
      } else if (step + 2 < NSTEP) {
        if constexpr (SB == 2) { WAITV2; } else { WAITV4; }
        S_BARRIER;
      } else {
        WAITV0;
        S_BARRIER;
      }
    }
  }

  // epilogue: bias + relu, bf16 out
#pragma unroll
  for (int nf = 0; nf < 4; ++nf) {
    int oc = ocB + wn * 64 + nf * 16 + lrow;
    float bv = bias[oc];
#pragma unroll
    for (int mf = 0; mf < WMF; ++mf) {
      int m0 = wm * (WMF * 16) + mf * 16 + lk * 4;
#pragma unroll
      for (int r = 0; r < 4; ++r) {
        float vv = acc[mf][nf][r] + bv;
        vv = vv > 0.f ? vv : 0.f;
        int px = P0 + m0 + r;
        if (POUT) {
          int bb = px >> 12, yy = (px >> 6) & 63, xx = px & 63;
          outp[((size_t)(bb * 66 + yy + 1) * 66 + xx + 1) * NOC + oc] =
              f2bf(vv);
        } else {
          outp[(size_t)px * NOC + oc] = f2bf(vv);
        }
      }
    }
  }
}

// ---------------- U[a,x,k] = sum_y relu_h2[a,y,x,k] (f32) -------------------
__global__ __launch_bounds__(256) void reduceU(
    const ushort* __restrict__ h2n, float* __restrict__ U) {
  int blk = blockIdx.x;          // a*64 + x
  int a = blk >> 6, xx = blk & 63;
  int t = threadIdx.x;
  int k0 = t * 4;
  const ushort* base = h2n + ((size_t)(a * 64) * 64 + xx) * 1024 + k0;
  float s0 = 0.f, s1 = 0.f, s2 = 0.f, s3 = 0.f;
#pragma unroll 4
  for (int y = 0; y < 64; ++y) {
    ushort4_t v = *reinterpret_cast<const ushort4_t*>(base + (size_t)y * 65536);
    s0 += bf2f(v[0]);
    s1 += bf2f(v[1]);
    s2 += bf2f(v[2]);
    s3 += bf2f(v[3]);
  }
  float* up = U + (size_t)(a * 64 + xx) * 1024 + k0;
  up[0] = s0; up[1] = s1; up[2] = s2; up[3] = s3;
}

// ---- T = U @ w3^T + 64*b3 ; h0/h63 = h2 rows 0/63 @ w3^T + b3 ; pooled -----
__global__ __launch_bounds__(256) void tailA(
    const ushort* __restrict__ h2n, const float* __restrict__ U,
    const float* __restrict__ w3, const float* __restrict__ b3,
    float* __restrict__ T, float* __restrict__ h0, float* __restrict__ h63,
    float* __restrict__ pooled) {
  int a = blockIdx.x >> 4, cg = blockIdx.x & 15;
  int t = threadIdx.x;
  int c4 = t >> 6, xx = t & 63;
  int c = cg * 4 + c4;
  const float* up = U + (size_t)(a * 64 + xx) * 1024;
  const ushort* r0 = h2n + ((size_t)(a * 64 + 0) * 64 + xx) * 1024;
  const ushort* r63 = h2n + ((size_t)(a * 64 + 63) * 64 + xx) * 1024;
  const float* w3r = w3 + c * 1024;
  float sT = 0.f, sa = 0.f, sb = 0.f;
  for (int k = 0; k < 1024; k += 4) {
    float4 w = *reinterpret_cast<const float4*>(w3r + k);
    float4 uu = *reinterpret_cast<const float4*>(up + k);
    ushort4_t v0 = *reinterpret_cast<const ushort4_t*>(r0 + k);
    ushort4_t v6 = *reinterpret_cast<const ushort4_t*>(r63 + k);
    sT = fmaf(uu.x, w.x, sT); sT = fmaf(uu.y, w.y, sT);
    sT = fmaf(uu.z, w.z, sT); sT = fmaf(uu.w, w.w, sT);
    sa = fmaf(bf2f(v0[0]), w.x, sa); sa = fmaf(bf2f(v0[1]), w.y, sa);
    sa = fmaf(bf2f(v0[2]), w.z, sa); sa = fmaf(bf2f(v0[3]), w.w, sa);
    sb = fmaf(bf2f(v6[0]), w.x, sb); sb = fmaf(bf2f(v6[1]), w.y, sb);
    sb = fmaf(bf2f(v6[2]), w.z, sb); sb = fmaf(bf2f(v6[3]), w.w, sb);
  }
  float bv = b3[c];
  float tfull = sT + 64.f * bv;
  T[(a * 64 + c) * 64 + xx] = tfull;
  h0[(a * 64 + c) * 64 + xx] = sa + bv;
  h63[(a * 64 + c) * 64 + xx] = sb + bv;
  float ps = tfull;
#pragma unroll
  for (int off = 32; off > 0; off >>= 1) ps += __shfl_down(ps, off);
  if (xx == 0) pooled[a * 64 + c] = ps * (1.f / 4096.f);
}

// --------- fused: dw (from pooled) -> xd (in reg) -> outpre -----------------
__global__ __launch_bounds__(256) void xdout(
    const float* __restrict__ T, const float* __restrict__ h0,
    const float* __restrict__ h63, const float* __restrict__ pooled,
    const float* __restrict__ wd, const float* __restrict__ bd,
    const float* __restrict__ w4, const float* __restrict__ b4,
    float* __restrict__ out) {
  int a = blockIdx.x >> 4, cg = blockIdx.x & 15;
  int t = threadIdx.x;
  __shared__ float dwl[4][4][9];
  if (t < 144) {
    int bb = t / 36, rem = t % 36, cj = rem / 9, p = rem % 9;
    int r = (cg * 4 + cj) * 9 + p;
    float s = bd[r];
    const float* pr = pooled + bb * 64;
    const float* wr = wd + r * 64;
    for (int cc = 0; cc < 64; ++cc) s = fmaf(pr[cc], wr[cc], s);
    dwl[bb][cj][p] = s;
  }
  __syncthreads();
  int c4 = t >> 6, xx = t & 63;
  int c = cg * 4 + c4;
  const float* Tp = T + (a * 64 + c) * 64;
  const float* H0 = h0 + (a * 64 + c) * 64;
  const float* H63 = h63 + (a * 64 + c) * 64;
  float xd4[4] = {0.f, 0.f, 0.f, 0.f};
#pragma unroll
  for (int j = 0; j < 3; ++j) {
    int xi = xx + j - 1;
    if (xi >= 0 && xi < 64) {
      float tv = Tp[xi];
      float S0 = tv - H63[xi];
      float S2 = tv - H0[xi];
#pragma unroll
      for (int bb = 0; bb < 4; ++bb) {
        xd4[bb] = fmaf(dwl[bb][c4][j], S0, xd4[bb]);
        xd4[bb] = fmaf(dwl[bb][c4][3 + j], tv, xd4[bb]);
        xd4[bb] = fmaf(dwl[bb][c4][6 + j], S2, xd4[bb]);
      }
    }
  }
  float* op = out + (size_t)a * 262144 + c * 64 + xx;
  for (int o = 0; o < 64; ++o) {
    float v = b4[o];
#pragma unroll
    for (int bb = 0; bb < 4; ++bb) v = fmaf(w4[o * 4 + bb], xd4[bb], v);
    op[o * 4096] = v;
  }
}

// ----------------- batchnorm stats per o over (a, c, x) ---------------------
__global__ __launch_bounds__(256) void bnstats_kernel(
    const float* __restrict__ out, float* __restrict__ stats) {
  int o = blockIdx.x;
  int tid = threadIdx.x;
  float s = 0.f, sq = 0.f;
  for (int i = tid; i < 4 * 64 * 64; i += 256) {
    int a = i >> 12;
    int rem = i & 4095;
    float v = out[(size_t)a * 262144 + o * 4096 + rem];
    s += v;
    sq = fmaf(v, v, sq);
  }
  __shared__ float ls[256], lq[256];
  ls[tid] = s; lq[tid] = sq;
  __syncthreads();
  for (int off = 128; off > 0; off >>= 1) {
    if (tid < off) { ls[tid] += ls[tid + off]; lq[tid] += lq[tid + off]; }
    __syncthreads();
  }
  if (tid == 0) {
    float mean = ls[0] * (1.f / 16384.f);
    float var = lq[0] * (1.f / 16384.f) - mean * mean;
    stats[o * 2] = mean;
    stats[o * 2 + 1] = rsqrtf(var + 1e-5f);
  }
}

__global__ __launch_bounds__(256) void bnapply_kernel(
    float* __restrict__ out, const float* __restrict__ stats,
    const float* __restrict__ gamma, const float* __restrict__ beta) {
  int idx = blockIdx.x * 256 + threadIdx.x;
  int o = (idx >> 12) & 63;
  float mean = stats[o * 2], rstd = stats[o * 2 + 1];
  out[idx] = (out[idx] - mean) * rstd * gamma[o] + beta[o];
}

// ---------------------------------------------------------------------------
extern "C" void kernel_launch(void* const* d_in, const int* in_sizes, int n_in,
                              void* d_out, int out_size, void* d_ws,
                              size_t ws_size, hipStream_t stream) {
  const float* x     = (const float*)d_in[0];
  const float* w1    = (const float*)d_in[1];
  const float* b1    = (const float*)d_in[2];
  const float* w2    = (const float*)d_in[3];
  const float* b2    = (const float*)d_in[4];
  const float* w3    = (const float*)d_in[5];
  const float* b3    = (const float*)d_in[6];
  const float* wd    = (const float*)d_in[7];
  const float* bd    = (const float*)d_in[8];
  const float* w4    = (const float*)d_in[9];
  const float* b4    = (const float*)d_in[10];
  const float* gamma = (const float*)d_in[11];
  const float* beta  = (const float*)d_in[12];
  float* out = (float*)d_out;

  // workspace carve (ushort offsets); h2n overlaps dead xn_pad region
  ushort* us = (ushort*)d_ws;
  ushort* h1n_pad = us;                       // 4,460,544 (+32K read slack)
  ushort* xn_pad  = us + 4493312;             // 1,115,136 (+slack, dies early)
  ushort* h2n     = us + 4493312;             // 16,777,216 (reuses xn region)
  ushort* w1p     = us + 21270528;            // 147,456
  ushort* w2p     = us + 21417984;            // 2,359,296
  float* fbase    = (float*)(us + 23777280);
  float* Ub     = fbase;                      // 262144
  float* Tb     = Ub + 262144;                // 16384
  float* h0b    = Tb + 16384;                 // 16384
  float* h63b   = h0b + 16384;                // 16384
  float* pooled = h63b + 16384;               // 256
  float* stats  = pooled + 256;               // 128

  pack_all<<<2392, 256, 0, stream>>>(x, w1, w2, xn_pad, w1p, w2p, h1n_pad);

  hipFuncSetAttribute(
      reinterpret_cast<const void*>(conv_gemm2<1, 256, 4, true>),
      hipFuncAttributeMaxDynamicSharedMemorySize, 106496);
  hipFuncSetAttribute(
      reinterpret_cast<const void*>(conv_gemm2<4, 1024, 8, false>),
      hipFuncAttributeMaxDynamicSharedMemorySize, 155648);

  conv_gemm2<1, 256, 4, true>
      <<<dim3(64, 2), 512, 106496, stream>>>(xn_pad, w1p, b1, h1n_pad);
  conv_gemm2<4, 1024, 8, false>
      <<<dim3(64, 4), 512, 155648, stream>>>(h1n_pad, w2p, b2, h2n);

  reduceU<<<256, 256, 0, stream>>>(h2n, Ub);
  tailA<<<64, 256, 0, stream>>>(h2n, Ub, w3, b3, Tb, h0b, h63b, pooled);
  xdout<<<64, 256, 0, stream>>>(Tb, h0b, h63b, pooled, wd, bd, w4, b4, out);
  bnstats_kernel<<<64, 256, 0, stream>>>(out, stats);
  bnapply_kernel<<<4096, 256, 0, stream>>>(out, stats, gamma, beta);
}

// Round 5
// 175.070 us; speedup vs baseline: 1.1394x; 1.1394x over previous
//
#include <hip/hip_runtime.h>
#include <hip/hip_bf16.h>
#include <math.h>

typedef unsigned short ushort;
typedef __attribute__((ext_vector_type(8))) short bf16x8;
typedef __attribute__((ext_vector_type(4))) float f32x4;
typedef __attribute__((ext_vector_type(8))) ushort ushort8;

__device__ inline ushort f2bf(float f) {
  __hip_bfloat16 h = __float2bfloat16(f);
  return *reinterpret_cast<ushort*>(&h);
}

typedef __attribute__((address_space(3))) unsigned int lds_u32;
typedef __attribute__((address_space(1))) const unsigned int glb_u32;
__device__ __forceinline__ void gl2lds16(const ushort* g, ushort* l) {
  __builtin_amdgcn_global_load_lds((glb_u32*)g, (lds_u32*)l, 16, 0, 0);
}

#define S_BARRIER asm volatile("s_barrier" ::: "memory")
#define WAITV0 asm volatile("s_waitcnt vmcnt(0)" ::: "memory")
#define WAITV4 asm volatile("s_waitcnt vmcnt(4)" ::: "memory")
#define LGKM0                                           \
  do {                                                  \
    asm volatile("s_waitcnt lgkmcnt(0)" ::: "memory");  \
    __builtin_amdgcn_sched_barrier(0);                  \
  } while (0)

// ============================ pack_all =====================================
// blocks [0,264): x NCHW f32 -> padded NHWC bf16 [b][66][66][64] (borders 0)
// blocks [264,328): w1 OIHW -> [tap][256][64]
// blocks [328,1352): w2 OIHW -> [tap][1024][256]
// blocks [1352,2392): zero borders of h1n_pad [b][66][66][256]
// blocks [2392,2649): zero U (262144 f) + pooled (256) + stats (128)
__global__ __launch_bounds__(256) void pack_all(
    const float* __restrict__ x, const float* __restrict__ w1,
    const float* __restrict__ w2, ushort* __restrict__ xn_pad,
    ushort* __restrict__ w1p, ushort* __restrict__ w2p,
    ushort* __restrict__ h1n_pad, float* __restrict__ zbase) {
  int blk = blockIdx.x;
  int tid = threadIdx.x;
  __shared__ float ld[64][65];
  if (blk < 264) {
    int b = blk / 66, yp = blk % 66;
    ushort* dst = xn_pad + (size_t)(b * 66 + yp) * 66 * 64;
    if (yp == 0 || yp == 65) {
      for (int i = tid; i < 66 * 64; i += 256) dst[i] = 0;
      return;
    }
    int y = yp - 1;
    int xx = tid & 63;
#pragma unroll
    for (int i = 0; i < 16; ++i) {
      int c = i * 4 + (tid >> 6);
      ld[c][xx] = x[((b * 64 + c) * 64 + y) * 64 + xx];
    }
    __syncthreads();
    for (int i = tid; i < 2 * 64; i += 256) {
      int side = i >> 6, c = i & 63;
      dst[(side ? 65 : 0) * 64 + c] = 0;
    }
    for (int u = tid; u < 64 * 8; u += 256) {
      int xp = u >> 3, cg = u & 7;
      ushort8 v;
#pragma unroll
      for (int j = 0; j < 8; ++j) v[j] = f2bf(ld[cg * 8 + j][xp]);
      *reinterpret_cast<ushort8*>(&dst[(xp + 1) * 64 + cg * 8]) = v;
    }
  } else if (blk < 328) {
    int idx = (blk - 264) * 256 + tid;  // OC=256, CIN=64
    float v[9];
#pragma unroll
    for (int t = 0; t < 9; ++t) v[t] = w1[idx * 9 + t];
    int oc = idx >> 6, c = idx & 63;
#pragma unroll
    for (int t = 0; t < 9; ++t) w1p[(t * 256 + oc) * 64 + c] = f2bf(v[t]);
  } else if (blk < 1352) {
    int idx = (blk - 328) * 256 + tid;  // OC=1024, CIN=256
    float v[9];
#pragma unroll
    for (int t = 0; t < 9; ++t) v[t] = w2[(size_t)idx * 9 + t];
    int oc = idx >> 8, c = idx & 255;
#pragma unroll
    for (int t = 0; t < 9; ++t)
      w2p[((size_t)t * 1024 + oc) * 256 + c] = f2bf(v[t]);
  } else if (blk < 2392) {
    int k = blk - 1352;  // 0..1039
    int b = k / 260, p = k % 260;
    int yp, xp;
    if (p < 66) { yp = 0; xp = p; }
    else if (p < 132) { yp = 65; xp = p - 66; }
    else if (p < 196) { yp = p - 132 + 1; xp = 0; }
    else { yp = p - 196 + 1; xp = 65; }
    h1n_pad[((size_t)(b * 66 + yp) * 66 + xp) * 256 + tid] = 0;
  } else {
    int i = (blk - 2392) * 1024 + tid * 4;  // zero 262528 floats
    if (i < 262528) {
      float4 z = {0.f, 0.f, 0.f, 0.f};
      *reinterpret_cast<float4*>(zbase + i) = z;
    }
  }
}

// ============== phase-split pipelined implicit-GEMM conv (3x3) ==============
// in_pad: [b][66][66][CIN] bf16, zero borders. wpack: [9][NOC][CIN].
// Per K64 step (tap): 2 phases of {ds_read frags, 2x global_load_lds,
// barrier, lgkmcnt(0), setprio+MFMA, barrier}; counted vmcnt(4) per step.
// POUT=true (conv1): writes padded NHWC bf16.
// POUT=false (conv2): epilogue accumulates relu into U[a,x,k] (f32 atomics)
//                     and writes rows 0/63 to h0raw/h63raw. No h2 tensor.
template<int C1B, int NOC, int WMF, int NWN, int NTHR, bool POUT>
__global__ __launch_bounds__(NTHR) void conv_gemm2p(
    const ushort* __restrict__ in_pad, const ushort* __restrict__ wpack,
    const float* __restrict__ bias, ushort* __restrict__ outp,
    float* __restrict__ U, float* __restrict__ h0raw,
    float* __restrict__ h63raw) {
  constexpr int CIN = C1B * 64;
  constexpr int NSTEP = C1B * 9;
  constexpr int NW = NTHR / 64;
  constexpr int NWM = NW / NWN;
  constexpr int BM = NWM * WMF * 16;
  constexpr int BN = NWN * 64;
  constexpr int RIMG = BM / 64;
  constexpr int ACH = (RIMG + 2) * 66 * 8;          // A 16B chunks
  constexpr int AIT = (ACH + NTHR - 1) / NTHR;
  constexpr int SB = (BN * 8) / NTHR;               // = 4
  constexpr int BUFU = BN * 64;                     // ushorts per B buffer
  extern __shared__ ushort lds[];
  ushort* Araw = lds;                               // ACH*16 bytes
  ushort* Bb = lds + ACH * 8;                       // 3 * BUFU
  int tid = threadIdx.x;
  int wid = tid >> 6, lane = tid & 63;
  int lrow = lane & 15, lk = lane >> 4;
  int wm = wid / NWN, wn = wid % NWN;
  int P0 = blockIdx.x * BM;
  int b = P0 >> 12;
  int y0 = (P0 & 4095) >> 6;
  int ocB = blockIdx.y * BN;
  f32x4 acc[WMF][4] = {};

  // precomputed per-thread staging offsets (loop-invariant)
  int aoff[AIT];
  bool aval[AIT];
#pragma unroll
  for (int it = 0; it < AIT; ++it) {
    int ch = it * NTHR + tid;
    aval[it] = ch < ACH;
    int slot = ch >> 3, cg = ch & 7;
    int xs = slot % 66;
    int cgp = cg ^ (xs & 7);
    aoff[it] = slot * CIN + cgp * 8;
  }
  int boff[SB];
#pragma unroll
  for (int it = 0; it < SB; ++it) {
    int ch = it * NTHR + tid;
    int oc = ch >> 3, cg = ch & 7;
    int cgp = cg ^ (oc & 7);
    boff[it] = oc * CIN + cgp * 8;
  }

  auto stageA = [&](int cb) {
    const ushort* asrc = in_pad + (size_t)(b * 66 + y0) * 66 * CIN + cb * 64;
#pragma unroll
    for (int it = 0; it < AIT; ++it)
      if (aval[it]) gl2lds16(asrc + aoff[it], Araw + (it * NTHR + wid * 64) * 8);
  };
  auto stageBhalf = [&](int sstep, int q, int half) {
    const ushort* wsrc =
        wpack + ((size_t)(sstep % 9) * NOC + ocB) * CIN + (sstep / 9) * 64;
    ushort* dbase = Bb + q * BUFU;
#pragma unroll
    for (int it = half * 2; it < half * 2 + 2; ++it)
      gl2lds16(wsrc + boff[it], dbase + (it * NTHR + wid * 64) * 8);
  };

  // prologue
  stageA(0);
  stageBhalf(0, 0, 0); stageBhalf(0, 0, 1);
  stageBhalf(1, 1, 0); stageBhalf(1, 1, 1);
  WAITV4;
  S_BARRIER;

#pragma unroll 1
  for (int cb = 0; cb < C1B; ++cb) {
#pragma unroll 1
    for (int t = 0; t < 9; ++t) {
      int step = cb * 9 + t;
      int ky = t / 3, kx = t - ky * 3;
      const ushort* bcur = Bb + (step % 3) * BUFU;
      bool pre = (step + 2 < NSTEP);
#pragma unroll
      for (int ph = 0; ph < 2; ++ph) {
        bf16x8 af[WMF], bfv[4];
#pragma unroll
        for (int mf = 0; mf < WMF; ++mf) {
          int m = wm * (WMF * 16) + mf * 16 + lrow;
          int xs = (m & 63) + kx;
          int slot = ((m >> 6) + ky) * 66 + xs;
          int ko = ((ph * 64 + lk * 16) ^ ((xs & 7) << 4)) >> 1;
          af[mf] = *reinterpret_cast<const bf16x8*>(Araw + slot * 64 + ko);
        }
#pragma unroll
        for (int nf = 0; nf < 4; ++nf) {
          int oc_l = wn * 64 + nf * 16 + lrow;
          int ko = ((ph * 64 + lk * 16) ^ ((oc_l & 7) << 4)) >> 1;
          bfv[nf] = *reinterpret_cast<const bf16x8*>(bcur + oc_l * 64 + ko);
        }
        if (pre) stageBhalf(step + 2, (step + 2) % 3, ph);
        S_BARRIER;
        LGKM0;
        __builtin_amdgcn_s_setprio(1);
#pragma unroll
        for (int mf = 0; mf < WMF; ++mf)
#pragma unroll
          for (int nf = 0; nf < 4; ++nf)
            acc[mf][nf] = __builtin_amdgcn_mfma_f32_16x16x32_bf16(
                af[mf], bfv[nf], acc[mf][nf], 0, 0, 0);
        __builtin_amdgcn_s_setprio(0);
        if (ph == 0) S_BARRIER;
      }
      if (t == 8 && cb + 1 < C1B) {
        S_BARRIER;
        stageA(cb + 1);
        WAITV0;
        S_BARRIER;
      } else if (pre) {
        WAITV4;
        S_BARRIER;
      } else {
        WAITV0;
        S_BARRIER;
      }
    }
  }

  // epilogue
#pragma unroll
  for (int nf = 0; nf < 4; ++nf) {
    int oc = ocB + wn * 64 + nf * 16 + lrow;
    float bv = bias[oc];
#pragma unroll
    for (int mf = 0; mf < WMF; ++mf) {
      int m0 = wm * (WMF * 16) + mf * 16 + lk * 4;
      int yrow = y0 + (m0 >> 6);
      int x0 = m0 & 63;
      if (POUT) {
#pragma unroll
        for (int r = 0; r < 4; ++r) {
          float vv = fmaxf(acc[mf][nf][r] + bv, 0.f);
          outp[((size_t)(b * 66 + yrow + 1) * 66 + x0 + r + 1) * NOC + oc] =
              f2bf(vv);
        }
      } else {
#pragma unroll
        for (int r = 0; r < 4; ++r) {
          float vv = fmaxf(acc[mf][nf][r] + bv, 0.f);
          size_t ui = ((size_t)(b * 64 + x0 + r)) * 1024 + oc;
          atomicAdd(&U[ui], vv);
          if (yrow == 0) h0raw[ui] = vv;
          else if (yrow == 63) h63raw[ui] = vv;
        }
      }
    }
  }
}

// ---- tailB: per (a,x): T = U@w3^T + 64*b3 ; h0/h63 rows @w3^T + b3 ; pooled
__global__ __launch_bounds__(256) void tailB(
    const float* __restrict__ U, const float* __restrict__ h0raw,
    const float* __restrict__ h63raw, const float* __restrict__ w3,
    const float* __restrict__ b3, float* __restrict__ T,
    float* __restrict__ h0, float* __restrict__ h63,
    float* __restrict__ pooled) {
  int blk = blockIdx.x;  // a*64 + xx
  int a = blk >> 6, xx = blk & 63;
  __shared__ float Ul[1024], R0[1024], R63[1024];
  int tid = threadIdx.x;
  const float* ub = U + (size_t)blk * 1024;
  const float* r0b = h0raw + (size_t)blk * 1024;
  const float* r6b = h63raw + (size_t)blk * 1024;
  *reinterpret_cast<float4*>(&Ul[tid * 4]) =
      *reinterpret_cast<const float4*>(&ub[tid * 4]);
  *reinterpret_cast<float4*>(&R0[tid * 4]) =
      *reinterpret_cast<const float4*>(&r0b[tid * 4]);
  *reinterpret_cast<float4*>(&R63[tid * 4]) =
      *reinterpret_cast<const float4*>(&r6b[tid * 4]);
  __syncthreads();
  int c = tid >> 2, g = tid & 3;
  const float* w3r = w3 + c * 1024 + g * 256;
  float sT = 0.f, s0 = 0.f, s6 = 0.f;
  for (int k = 0; k < 256; k += 4) {
    float4 w = *reinterpret_cast<const float4*>(w3r + k);
    int kk = g * 256 + k;
    float4 uu = *reinterpret_cast<const float4*>(&Ul[kk]);
    float4 a0 = *reinterpret_cast<const float4*>(&R0[kk]);
    float4 a6 = *reinterpret_cast<const float4*>(&R63[kk]);
    sT = fmaf(uu.x, w.x, sT); sT = fmaf(uu.y, w.y, sT);
    sT = fmaf(uu.z, w.z, sT); sT = fmaf(uu.w, w.w, sT);
    s0 = fmaf(a0.x, w.x, s0); s0 = fmaf(a0.y, w.y, s0);
    s0 = fmaf(a0.z, w.z, s0); s0 = fmaf(a0.w, w.w, s0);
    s6 = fmaf(a6.x, w.x, s6); s6 = fmaf(a6.y, w.y, s6);
    s6 = fmaf(a6.z, w.z, s6); s6 = fmaf(a6.w, w.w, s6);
  }
  sT += __shfl_xor(sT, 1); sT += __shfl_xor(sT, 2);
  s0 += __shfl_xor(s0, 1); s0 += __shfl_xor(s0, 2);
  s6 += __shfl_xor(s6, 1); s6 += __shfl_xor(s6, 2);
  if (g == 0) {
    float bv = b3[c];
    float tf = sT + 64.f * bv;
    T[(a * 64 + c) * 64 + xx] = tf;
    h0[(a * 64 + c) * 64 + xx] = s0 + bv;
    h63[(a * 64 + c) * 64 + xx] = s6 + bv;
    atomicAdd(&pooled[a * 64 + c], tf * (1.f / 4096.f));
  }
}

// --------- fused: dw -> xd (in reg) -> outpre -> bn partial stats -----------
__global__ __launch_bounds__(256) void xdout(
    const float* __restrict__ T, const float* __restrict__ h0,
    const float* __restrict__ h63, const float* __restrict__ pooled,
    const float* __restrict__ wd, const float* __restrict__ bd,
    const float* __restrict__ w4, const float* __restrict__ b4,
    float* __restrict__ out, float* __restrict__ stats) {
  int a = blockIdx.x >> 4, cg = blockIdx.x & 15;
  int t = threadIdx.x;
  __shared__ float dwl[4][4][9];
  __shared__ float redS[256], redQ[256];
  if (t < 144) {
    int bb = t / 36, rem = t % 36, cj = rem / 9, p = rem % 9;
    int r = (cg * 4 + cj) * 9 + p;
    float s = bd[r];
    const float* pr = pooled + bb * 64;
    const float* wr = wd + r * 64;
    for (int cc = 0; cc < 64; ++cc) s = fmaf(pr[cc], wr[cc], s);
    dwl[bb][cj][p] = s;
  }
  __syncthreads();
  int c4 = t >> 6, xx = t & 63;
  int lane = t & 63, wv = t >> 6;
  int c = cg * 4 + c4;
  const float* Tp = T + (a * 64 + c) * 64;
  const float* H0 = h0 + (a * 64 + c) * 64;
  const float* H63 = h63 + (a * 64 + c) * 64;
  float xd4[4] = {0.f, 0.f, 0.f, 0.f};
#pragma unroll
  for (int j = 0; j < 3; ++j) {
    int xi = xx + j - 1;
    if (xi >= 0 && xi < 64) {
      float tv = Tp[xi];
      float S0 = tv - H63[xi];
      float S2 = tv - H0[xi];
#pragma unroll
      for (int bb = 0; bb < 4; ++bb) {
        xd4[bb] = fmaf(dwl[bb][c4][j], S0, xd4[bb]);
        xd4[bb] = fmaf(dwl[bb][c4][3 + j], tv, xd4[bb]);
        xd4[bb] = fmaf(dwl[bb][c4][6 + j], S2, xd4[bb]);
      }
    }
  }
  float* op = out + (size_t)a * 262144 + c * 64 + xx;
  for (int o = 0; o < 64; ++o) {
    float v = b4[o];
#pragma unroll
    for (int bb = 0; bb < 4; ++bb) v = fmaf(w4[o * 4 + bb], xd4[bb], v);
    op[o * 4096] = v;
    float sv = v, sq = v * v;
#pragma unroll
    for (int off = 32; off > 0; off >>= 1) {
      sv += __shfl_down(sv, off);
      sq += __shfl_down(sq, off);
    }
    if (lane == 0) { redS[wv * 64 + o] = sv; redQ[wv * 64 + o] = sq; }
  }
  __syncthreads();
  if (t < 64) {
    float S = redS[t] + redS[64 + t] + redS[128 + t] + redS[192 + t];
    float Q = redQ[t] + redQ[64 + t] + redQ[128 + t] + redQ[192 + t];
    atomicAdd(&stats[t], S);
    atomicAdd(&stats[64 + t], Q);
  }
}

// ------------------- batchnorm apply (stats from xdout) ---------------------
__global__ __launch_bounds__(256) void bnapply_kernel(
    float* __restrict__ out, const float* __restrict__ stats,
    const float* __restrict__ gamma, const float* __restrict__ beta) {
  int idx = blockIdx.x * 256 + threadIdx.x;
  int o = (idx >> 12) & 63;
  float mean = stats[o] * (1.f / 16384.f);
  float var = stats[64 + o] * (1.f / 16384.f) - mean * mean;
  float rstd = rsqrtf(var + 1e-5f);
  out[idx] = (out[idx] - mean) * rstd * gamma[o] + beta[o];
}

// ---------------------------------------------------------------------------
extern "C" void kernel_launch(void* const* d_in, const int* in_sizes, int n_in,
                              void* d_out, int out_size, void* d_ws,
                              size_t ws_size, hipStream_t stream) {
  const float* x     = (const float*)d_in[0];
  const float* w1    = (const float*)d_in[1];
  const float* b1    = (const float*)d_in[2];
  const float* w2    = (const float*)d_in[3];
  const float* b2    = (const float*)d_in[4];
  const float* w3    = (const float*)d_in[5];
  const float* b3    = (const float*)d_in[6];
  const float* wd    = (const float*)d_in[7];
  const float* bd    = (const float*)d_in[8];
  const float* w4    = (const float*)d_in[9];
  const float* b4    = (const float*)d_in[10];
  const float* gamma = (const float*)d_in[11];
  const float* beta  = (const float*)d_in[12];
  float* out = (float*)d_out;

  // workspace carve (ushort region, then float region)
  ushort* us = (ushort*)d_ws;
  ushort* h1n_pad = us;                       // 4,460,544
  ushort* xn_pad  = us + 4460544;             // 1,115,136
  ushort* w1p     = us + 5575680;             // 147,456
  ushort* w2p     = us + 5723136;             // 2,359,296
  float* fbase    = (float*)(us + 8082432);
  float* Ub      = fbase;                     // 262144  (zeroed each call)
  float* pooled  = Ub + 262144;               // 256     (zeroed)
  float* stats   = pooled + 256;              // 128     (zeroed)
  float* Tb      = stats + 128;               // 16384
  float* h0b     = Tb + 16384;                // 16384
  float* h63b    = h0b + 16384;               // 16384
  float* h0raw   = h63b + 16384;              // 262144
  float* h63raw  = h0raw + 262144;            // 262144

  pack_all<<<2649, 256, 0, stream>>>(x, w1, w2, xn_pad, w1p, w2p, h1n_pad, Ub);

  // conv1: C1B=1, NOC=256, WMF=4, NWN=2, 256 thr -> BM=128, BN=128
  // LDS: A 33792 + 3*16384 = 82944
  hipFuncSetAttribute(
      reinterpret_cast<const void*>(conv_gemm2p<1, 256, 4, 2, 256, true>),
      hipFuncAttributeMaxDynamicSharedMemorySize, 82944);
  // conv2: C1B=4, NOC=1024, WMF=8, NWN=4, 512 thr -> BM=256, BN=256
  // LDS: A 50688 + 3*32768 = 148992
  hipFuncSetAttribute(
      reinterpret_cast<const void*>(conv_gemm2p<4, 1024, 8, 4, 512, false>),
      hipFuncAttributeMaxDynamicSharedMemorySize, 148992);

  conv_gemm2p<1, 256, 4, 2, 256, true>
      <<<dim3(128, 2), 256, 82944, stream>>>(xn_pad, w1p, b1, h1n_pad,
                                             nullptr, nullptr, nullptr);
  conv_gemm2p<4, 1024, 8, 4, 512, false>
      <<<dim3(64, 4), 512, 148992, stream>>>(h1n_pad, w2p, b2, nullptr,
                                             Ub, h0raw, h63raw);

  tailB<<<256, 256, 0, stream>>>(Ub, h0raw, h63raw, w3, b3, Tb, h0b, h63b,
                                 pooled);
  xdout<<<64, 256, 0, stream>>>(Tb, h0b, h63b, pooled, wd, bd, w4, b4, out,
                                stats);
  bnapply_kernel<<<4096, 256, 0, stream>>>(out, stats, gamma, beta);
}

// Round 6
// 138.732 us; speedup vs baseline: 1.4379x; 1.2619x over previous
//
#include <hip/hip_runtime.h>
#include <hip/hip_bf16.h>
#include <math.h>

typedef unsigned short ushort;
typedef __attribute__((ext_vector_type(8))) short bf16x8;
typedef __attribute__((ext_vector_type(4))) float f32x4;
typedef __attribute__((ext_vector_type(8))) ushort ushort8;
typedef __attribute__((ext_vector_type(4))) ushort ushort4_t;

__device__ inline ushort f2bf(float f) {
  __hip_bfloat16 h = __float2bfloat16(f);
  return *reinterpret_cast<ushort*>(&h);
}
__device__ inline float bf2f(ushort u) {
  unsigned int v = ((unsigned int)u) << 16;
  return __builtin_bit_cast(float, v);
}

typedef __attribute__((address_space(3))) unsigned int lds_u32;
typedef __attribute__((address_space(1))) const unsigned int glb_u32;
__device__ __forceinline__ void gl2lds16(const ushort* g, ushort* l) {
  __builtin_amdgcn_global_load_lds((glb_u32*)g, (lds_u32*)l, 16, 0, 0);
}

#define S_BARRIER asm volatile("s_barrier" ::: "memory")
#define WAITV0 asm volatile("s_waitcnt vmcnt(0)" ::: "memory")
#define WAITV2 asm volatile("s_waitcnt vmcnt(2)" ::: "memory")
#define WAITV4 asm volatile("s_waitcnt vmcnt(4)" ::: "memory")

// ============================ pack_all =====================================
// blocks [0,264): x NCHW f32 -> padded NHWC bf16 [b][66][66][64] (borders 0)
// blocks [264,328): w1 OIHW -> [tap][256][64]
// blocks [328,1352): w2 OIHW -> [tap][1024][256]
// blocks [1352,2392): zero borders of h1n_pad [b][66][66][256]
// block 2392: zero pooled (256 f) + stats (128 f)
__global__ __launch_bounds__(256) void pack_all(
    const float* __restrict__ x, const float* __restrict__ w1,
    const float* __restrict__ w2, ushort* __restrict__ xn_pad,
    ushort* __restrict__ w1p, ushort* __restrict__ w2p,
    ushort* __restrict__ h1n_pad, float* __restrict__ zbase) {
  int blk = blockIdx.x;
  int tid = threadIdx.x;
  __shared__ float ld[64][65];
  if (blk < 264) {
    int b = blk / 66, yp = blk % 66;
    ushort* dst = xn_pad + (size_t)(b * 66 + yp) * 66 * 64;
    if (yp == 0 || yp == 65) {
      for (int i = tid; i < 66 * 64; i += 256) dst[i] = 0;
      return;
    }
    int y = yp - 1;
    int xx = tid & 63;
#pragma unroll
    for (int i = 0; i < 16; ++i) {
      int c = i * 4 + (tid >> 6);
      ld[c][xx] = x[((b * 64 + c) * 64 + y) * 64 + xx];
    }
    __syncthreads();
    for (int i = tid; i < 2 * 64; i += 256) {
      int side = i >> 6, c = i & 63;
      dst[(side ? 65 : 0) * 64 + c] = 0;
    }
    for (int u = tid; u < 64 * 8; u += 256) {
      int xp = u >> 3, cg = u & 7;
      ushort8 v;
#pragma unroll
      for (int j = 0; j < 8; ++j) v[j] = f2bf(ld[cg * 8 + j][xp]);
      *reinterpret_cast<ushort8*>(&dst[(xp + 1) * 64 + cg * 8]) = v;
    }
  } else if (blk < 328) {
    int idx = (blk - 264) * 256 + tid;  // OC=256, CIN=64
    float v[9];
#pragma unroll
    for (int t = 0; t < 9; ++t) v[t] = w1[idx * 9 + t];
    int oc = idx >> 6, c = idx & 63;
#pragma unroll
    for (int t = 0; t < 9; ++t) w1p[(t * 256 + oc) * 64 + c] = f2bf(v[t]);
  } else if (blk < 1352) {
    int idx = (blk - 328) * 256 + tid;  // OC=1024, CIN=256
    float v[9];
#pragma unroll
    for (int t = 0; t < 9; ++t) v[t] = w2[(size_t)idx * 9 + t];
    int oc = idx >> 8, c = idx & 255;
#pragma unroll
    for (int t = 0; t < 9; ++t)
      w2p[((size_t)t * 1024 + oc) * 256 + c] = f2bf(v[t]);
  } else if (blk < 2392) {
    int k = blk - 1352;  // 0..1039
    int b = k / 260, p = k % 260;
    int yp, xp;
    if (p < 66) { yp = 0; xp = p; }
    else if (p < 132) { yp = 65; xp = p - 66; }
    else if (p < 196) { yp = p - 132 + 1; xp = 0; }
    else { yp = p - 196 + 1; xp = 65; }
    h1n_pad[((size_t)(b * 66 + yp) * 66 + xp) * 256 + tid] = 0;
  } else {
    if (tid < 96) {
      float4 z = {0.f, 0.f, 0.f, 0.f};
      *reinterpret_cast<float4*>(zbase + tid * 4) = z;
    }
  }
}

// ================= pipelined implicit-GEMM conv (3x3, pad 1) ================
// Proven round-4 loop structure (78us, MfmaUtil 39%, 0 bank conflicts).
// in_pad: [b][66][66][CIN] bf16, zero borders. wpack: [9][NOC][CIN].
// WMF=4: BM=256, BN=128, waves 4Mx2N (wave tile 64x64)   [conv1]
// WMF=8: BM=256, BN=256, waves 2Mx4N (wave tile 128x64)  [conv2]
// K-step = (cb, tap) = 64. A staged per cb (swizzled src), B triple-buffered
// via global_load_lds, prefetch distance 2, counted vmcnt. setprio on MFMA.
// POUT=true: padded NHWC bf16 out. POUT=false: dense [px][NOC] bf16 out.
template<int C1B, int NOC, int WMF, bool POUT>
__global__ __launch_bounds__(512) void conv_gemm2(
    const ushort* __restrict__ in_pad, const ushort* __restrict__ wpack,
    const float* __restrict__ bias, ushort* __restrict__ outp) {
  constexpr int CIN = C1B * 64;
  constexpr int NSTEP = C1B * 9;
  constexpr int NWN = (WMF == 8) ? 4 : 2;
  constexpr int BN = NWN * 64;
  constexpr int SB = BN / 64;        // stageB gl2lds16 per thread
  constexpr int BUFU = BN * 64;      // ushorts per B buffer
  extern __shared__ ushort lds[];
  ushort* Araw = lds;                // 3584 chunks x 16B = 57344 B (incl slack)
  ushort* Bb = lds + 28672;          // 3 x BUFU ushorts
  int tid = threadIdx.x;
  int wid = tid >> 6, lane = tid & 63;
  int lrow = lane & 15, lk = lane >> 4;
  int wm = wid / NWN, wn = wid % NWN;
  int P0 = blockIdx.x * 256;
  int b = P0 >> 12;
  int y0 = (P0 & 4095) >> 6;
  int ocB = blockIdx.y * BN;
  f32x4 acc[WMF][4] = {};

  auto stageA = [&](int cb) {
    const ushort* asrc = in_pad + (size_t)(b * 66 + y0) * 66 * CIN + cb * 64;
#pragma unroll
    for (int it = 0; it < 7; ++it) {
      int basech = it * 512 + wid * 64;
      int ch = basech + lane;
      int ry = ch / 528, rem = ch % 528;
      int xs = rem >> 3, cg = rem & 7;
      int cgp = cg ^ (xs & 7);
      gl2lds16(asrc + (size_t)(ry * 66 + xs) * CIN + cgp * 8,
               Araw + basech * 8);
    }
  };
  auto stageB = [&](int sstep, int q) {
    int st = sstep % 9;
    int scb = sstep / 9;
    const ushort* wsrc = wpack + ((size_t)st * NOC + ocB) * CIN + scb * 64;
    ushort* dbase = Bb + q * BUFU;
#pragma unroll
    for (int it = 0; it < SB; ++it) {
      int basech = it * 512 + wid * 64;
      int ch = basech + lane;
      int oc = ch >> 3, cg = ch & 7;
      int cgp = cg ^ (oc & 7);
      gl2lds16(wsrc + (size_t)oc * CIN + cgp * 8, dbase + basech * 8);
    }
  };

  // prologue
  stageA(0);
  stageB(0, 0);
  stageB(1, 1);
  if constexpr (SB == 2) { WAITV2; } else { WAITV4; }
  S_BARRIER;

#pragma unroll 1
  for (int cb = 0; cb < C1B; ++cb) {
#pragma unroll 1
    for (int t = 0; t < 9; ++t) {
      int step = cb * 9 + t;
      int cur = step % 3;
      if (step + 2 < NSTEP) stageB(step + 2, (step + 2) % 3);
      int ky = t / 3, kx = t - ky * 3;
      const ushort* bcur = Bb + cur * BUFU;
#pragma unroll
      for (int ks = 0; ks < 2; ++ks) {
        bf16x8 af[WMF], bfv[4];
#pragma unroll
        for (int mf = 0; mf < WMF; ++mf) {
          int mwave = mf * 16 + lrow;
          int xs = (mwave & 63) + kx;
          int row = (wm * (WMF / 4) + (mwave >> 6) + ky) * 66 + xs;
          int kboff = (ks * 64 + lk * 16) ^ ((xs & 7) << 4);
          af[mf] =
              *reinterpret_cast<const bf16x8*>(Araw + row * 64 + (kboff >> 1));
        }
#pragma unroll
        for (int nf = 0; nf < 4; ++nf) {
          int oc_l = wn * 64 + nf * 16 + lrow;
          int kboff = (ks * 64 + lk * 16) ^ ((oc_l & 7) << 4);
          bfv[nf] =
              *reinterpret_cast<const bf16x8*>(bcur + oc_l * 64 + (kboff >> 1));
        }
        __builtin_amdgcn_s_setprio(1);
#pragma unroll
        for (int mf = 0; mf < WMF; ++mf)
#pragma unroll
          for (int nf = 0; nf < 4; ++nf)
            acc[mf][nf] = __builtin_amdgcn_mfma_f32_16x16x32_bf16(
                af[mf], bfv[nf], acc[mf][nf], 0, 0, 0);
        __builtin_amdgcn_s_setprio(0);
      }
      if (t == 8 && cb + 1 < C1B) {
        S_BARRIER;          // all waves done reading Araw
        stageA(cb + 1);
        WAITV0;
        S_BARRIER;
      } else if (step + 2 < NSTEP) {
        if constexpr (SB == 2) { WAITV2; } else { WAITV4; }
        S_BARRIER;
      } else {
        WAITV0;
        S_BARRIER;
      }
    }
  }

  // epilogue: bias + relu, bf16 out
#pragma unroll
  for (int nf = 0; nf < 4; ++nf) {
    int oc = ocB + wn * 64 + nf * 16 + lrow;
    float bv = bias[oc];
#pragma unroll
    for (int mf = 0; mf < WMF; ++mf) {
      int m0 = wm * (WMF * 16) + mf * 16 + lk * 4;
#pragma unroll
      for (int r = 0; r < 4; ++r) {
        float vv = acc[mf][nf][r] + bv;
        vv = vv > 0.f ? vv : 0.f;
        int px = P0 + m0 + r;
        if (POUT) {
          int bb = px >> 12, yy = (px >> 6) & 63, xx = px & 63;
          outp[((size_t)(bb * 66 + yy + 1) * 66 + xx + 1) * NOC + oc] =
              f2bf(vv);
        } else {
          outp[(size_t)px * NOC + oc] = f2bf(vv);
        }
      }
    }
  }
}

// ---------------- U[a,x,k] = sum_y relu_h2[a,y,x,k] (f32) -------------------
__global__ __launch_bounds__(256) void reduceU(
    const ushort* __restrict__ h2n, float* __restrict__ U) {
  int blk = blockIdx.x;          // a*64 + x
  int a = blk >> 6, xx = blk & 63;
  int t = threadIdx.x;
  int k0 = t * 4;
  const ushort* base = h2n + ((size_t)(a * 64) * 64 + xx) * 1024 + k0;
  float s0 = 0.f, s1 = 0.f, s2 = 0.f, s3 = 0.f;
#pragma unroll 4
  for (int y = 0; y < 64; ++y) {
    ushort4_t v = *reinterpret_cast<const ushort4_t*>(base + (size_t)y * 65536);
    s0 += bf2f(v[0]);
    s1 += bf2f(v[1]);
    s2 += bf2f(v[2]);
    s3 += bf2f(v[3]);
  }
  float* up = U + (size_t)(a * 64 + xx) * 1024 + k0;
  up[0] = s0; up[1] = s1; up[2] = s2; up[3] = s3;
}

// ---- tailB: per (a,x): T = U@w3^T + 64*b3 ; rows 0/63 @w3^T + b3 ; pooled --
__global__ __launch_bounds__(256) void tailB(
    const float* __restrict__ U, const ushort* __restrict__ h2n,
    const float* __restrict__ w3, const float* __restrict__ b3,
    float* __restrict__ T, float* __restrict__ h0, float* __restrict__ h63,
    float* __restrict__ pooled) {
  int blk = blockIdx.x;  // a*64 + xx
  int a = blk >> 6, xx = blk & 63;
  __shared__ float Ul[1024], R0[1024], R63[1024];
  int tid = threadIdx.x;
  const float* ub = U + (size_t)blk * 1024;
  const ushort* r0b = h2n + ((size_t)(a * 4096 + xx)) * 1024;
  const ushort* r6b = h2n + ((size_t)(a * 4096 + 63 * 64 + xx)) * 1024;
  *reinterpret_cast<float4*>(&Ul[tid * 4]) =
      *reinterpret_cast<const float4*>(&ub[tid * 4]);
  ushort4_t v0 = *reinterpret_cast<const ushort4_t*>(r0b + tid * 4);
  ushort4_t v6 = *reinterpret_cast<const ushort4_t*>(r6b + tid * 4);
#pragma unroll
  for (int j = 0; j < 4; ++j) {
    R0[tid * 4 + j] = bf2f(v0[j]);
    R63[tid * 4 + j] = bf2f(v6[j]);
  }
  __syncthreads();
  int c = tid >> 2, g = tid & 3;
  const float* w3r = w3 + c * 1024 + g * 256;
  float sT = 0.f, s0 = 0.f, s6 = 0.f;
  for (int k = 0; k < 256; k += 4) {
    float4 w = *reinterpret_cast<const float4*>(w3r + k);
    int kk = g * 256 + k;
    float4 uu = *reinterpret_cast<const float4*>(&Ul[kk]);
    float4 a0 = *reinterpret_cast<const float4*>(&R0[kk]);
    float4 a6 = *reinterpret_cast<const float4*>(&R63[kk]);
    sT = fmaf(uu.x, w.x, sT); sT = fmaf(uu.y, w.y, sT);
    sT = fmaf(uu.z, w.z, sT); sT = fmaf(uu.w, w.w, sT);
    s0 = fmaf(a0.x, w.x, s0); s0 = fmaf(a0.y, w.y, s0);
    s0 = fmaf(a0.z, w.z, s0); s0 = fmaf(a0.w, w.w, s0);
    s6 = fmaf(a6.x, w.x, s6); s6 = fmaf(a6.y, w.y, s6);
    s6 = fmaf(a6.z, w.z, s6); s6 = fmaf(a6.w, w.w, s6);
  }
  sT += __shfl_xor(sT, 1); sT += __shfl_xor(sT, 2);
  s0 += __shfl_xor(s0, 1); s0 += __shfl_xor(s0, 2);
  s6 += __shfl_xor(s6, 1); s6 += __shfl_xor(s6, 2);
  if (g == 0) {
    float bv = b3[c];
    float tf = sT + 64.f * bv;
    T[(a * 64 + c) * 64 + xx] = tf;
    h0[(a * 64 + c) * 64 + xx] = s0 + bv;
    h63[(a * 64 + c) * 64 + xx] = s6 + bv;
    atomicAdd(&pooled[a * 64 + c], tf * (1.f / 4096.f));
  }
}

// --------- fused: dw -> xd (in reg) -> outpre -> bn partial stats -----------
__global__ __launch_bounds__(256) void xdout(
    const float* __restrict__ T, const float* __restrict__ h0,
    const float* __restrict__ h63, const float* __restrict__ pooled,
    const float* __restrict__ wd, const float* __restrict__ bd,
    const float* __restrict__ w4, const float* __restrict__ b4,
    float* __restrict__ out, float* __restrict__ stats) {
  int a = blockIdx.x >> 4, cg = blockIdx.x & 15;
  int t = threadIdx.x;
  __shared__ float dwl[4][4][9];
  __shared__ float redS[256], redQ[256];
  if (t < 144) {
    int bb = t / 36, rem = t % 36, cj = rem / 9, p = rem % 9;
    int r = (cg * 4 + cj) * 9 + p;
    float s = bd[r];
    const float* pr = pooled + bb * 64;
    const float* wr = wd + r * 64;
    for (int cc = 0; cc < 64; ++cc) s = fmaf(pr[cc], wr[cc], s);
    dwl[bb][cj][p] = s;
  }
  __syncthreads();
  int c4 = t >> 6, xx = t & 63;
  int lane = t & 63, wv = t >> 6;
  int c = cg * 4 + c4;
  const float* Tp = T + (a * 64 + c) * 64;
  const float* H0 = h0 + (a * 64 + c) * 64;
  const float* H63 = h63 + (a * 64 + c) * 64;
  float xd4[4] = {0.f, 0.f, 0.f, 0.f};
#pragma unroll
  for (int j = 0; j < 3; ++j) {
    int xi = xx + j - 1;
    if (xi >= 0 && xi < 64) {
      float tv = Tp[xi];
      float S0 = tv - H63[xi];
      float S2 = tv - H0[xi];
#pragma unroll
      for (int bb = 0; bb < 4; ++bb) {
        xd4[bb] = fmaf(dwl[bb][c4][j], S0, xd4[bb]);
        xd4[bb] = fmaf(dwl[bb][c4][3 + j], tv, xd4[bb]);
        xd4[bb] = fmaf(dwl[bb][c4][6 + j], S2, xd4[bb]);
      }
    }
  }
  float* op = out + (size_t)a * 262144 + c * 64 + xx;
  for (int o = 0; o < 64; ++o) {
    float v = b4[o];
#pragma unroll
    for (int bb = 0; bb < 4; ++bb) v = fmaf(w4[o * 4 + bb], xd4[bb], v);
    op[o * 4096] = v;
    float sv = v, sq = v * v;
#pragma unroll
    for (int off = 32; off > 0; off >>= 1) {
      sv += __shfl_down(sv, off);
      sq += __shfl_down(sq, off);
    }
    if (lane == 0) { redS[wv * 64 + o] = sv; redQ[wv * 64 + o] = sq; }
  }
  __syncthreads();
  if (t < 64) {
    float S = redS[t] + redS[64 + t] + redS[128 + t] + redS[192 + t];
    float Q = redQ[t] + redQ[64 + t] + redQ[128 + t] + redQ[192 + t];
    atomicAdd(&stats[t], S);
    atomicAdd(&stats[64 + t], Q);
  }
}

// ------------------- batchnorm apply (stats from xdout) ---------------------
__global__ __launch_bounds__(256) void bnapply_kernel(
    float* __restrict__ out, const float* __restrict__ stats,
    const float* __restrict__ gamma, const float* __restrict__ beta) {
  int idx = blockIdx.x * 256 + threadIdx.x;
  int o = (idx >> 12) & 63;
  float mean = stats[o] * (1.f / 16384.f);
  float var = stats[64 + o] * (1.f / 16384.f) - mean * mean;
  float rstd = rsqrtf(var + 1e-5f);
  out[idx] = (out[idx] - mean) * rstd * gamma[o] + beta[o];
}

// ---------------------------------------------------------------------------
extern "C" void kernel_launch(void* const* d_in, const int* in_sizes, int n_in,
                              void* d_out, int out_size, void* d_ws,
                              size_t ws_size, hipStream_t stream) {
  const float* x     = (const float*)d_in[0];
  const float* w1    = (const float*)d_in[1];
  const float* b1    = (const float*)d_in[2];
  const float* w2    = (const float*)d_in[3];
  const float* b2    = (const float*)d_in[4];
  const float* w3    = (const float*)d_in[5];
  const float* b3    = (const float*)d_in[6];
  const float* wd    = (const float*)d_in[7];
  const float* bd    = (const float*)d_in[8];
  const float* w4    = (const float*)d_in[9];
  const float* b4    = (const float*)d_in[10];
  const float* gamma = (const float*)d_in[11];
  const float* beta  = (const float*)d_in[12];
  float* out = (float*)d_out;

  // workspace carve (ushort offsets); h2n overlaps dead xn_pad region
  ushort* us = (ushort*)d_ws;
  ushort* h1n_pad = us;                       // 4,460,544
  ushort* xn_pad  = us + 4460544;             // 1,115,136 (dies after conv1)
  ushort* h2n     = us + 4460544;             // 16,777,216 (reuses xn region)
  ushort* w1p     = us + 21237760;            // 147,456
  ushort* w2p     = us + 21385216;            // 2,359,296 -> ends 23,744,512
  float* fbase    = (float*)(us + 23744512);
  float* Ub      = fbase;                     // 262144
  float* pooled  = Ub + 262144;               // 256  (zeroed each call)
  float* stats   = pooled + 256;              // 128  (zeroed each call)
  float* Tb      = stats + 128;               // 16384
  float* h0b     = Tb + 16384;                // 16384
  float* h63b    = h0b + 16384;               // 16384

  pack_all<<<2393, 256, 0, stream>>>(x, w1, w2, xn_pad, w1p, w2p, h1n_pad,
                                     pooled);

  // conv1: BM=256, BN=128; LDS = 57344 (A incl slack) + 3*16384 = 106496
  hipFuncSetAttribute(
      reinterpret_cast<const void*>(conv_gemm2<1, 256, 4, true>),
      hipFuncAttributeMaxDynamicSharedMemorySize, 106496);
  // conv2: BM=256, BN=256; LDS = 57344 + 3*32768 = 155648
  hipFuncSetAttribute(
      reinterpret_cast<const void*>(conv_gemm2<4, 1024, 8, false>),
      hipFuncAttributeMaxDynamicSharedMemorySize, 155648);

  conv_gemm2<1, 256, 4, true>
      <<<dim3(64, 2), 512, 106496, stream>>>(xn_pad, w1p, b1, h1n_pad);
  conv_gemm2<4, 1024, 8, false>
      <<<dim3(64, 4), 512, 155648, stream>>>(h1n_pad, w2p, b2, h2n);

  reduceU<<<256, 256, 0, stream>>>(h2n, Ub);
  tailB<<<256, 256, 0, stream>>>(Ub, h2n, w3, b3, Tb, h0b, h63b, pooled);
  xdout<<<64, 256, 0, stream>>>(Tb, h0b, h63b, pooled, wd, bd, w4, b4, out,
                                stats);
  bnapply_kernel<<<4096, 256, 0, stream>>>(out, stats, gamma, beta);
}